// Round 1
// baseline (624.850 us; speedup 1.0000x reference)
//
#include <hip/hip_runtime.h>

#define NB 65536
#define ND 8
#define NE 16
#define NH 80
#define NF 9
#define NV 100000
#define NIN 160

// ws layout in 4-byte units
#define WS_W1F    0          // 102400 floats: fused W1 per domain (D,IN,H)
#define WS_B1F    102400     // 640
#define WS_W2F    103040     // 640
#define WS_B2F    103680     // 8
#define WS_COUNTS 103688     // 8 ints
#define WS_CURS   103696     // 8 ints
#define WS_OFFS   103704     // 8 ints
#define WS_LIST   103712     // up to 65536 ints

__global__ void k_fuse(const float* __restrict__ sw1, const float* __restrict__ dw1,
                       const float* __restrict__ sb1, const float* __restrict__ db1,
                       const float* __restrict__ sw2, const float* __restrict__ dw2,
                       const float* __restrict__ sb2, const float* __restrict__ db2,
                       float* __restrict__ wsf, int* __restrict__ counts) {
  int t = blockIdx.x * 256 + threadIdx.x;
  if (t < ND * NIN * NH) wsf[WS_W1F + t] = sw1[t % (NIN * NH)] * dw1[t];
  if (t < ND * NH) {
    wsf[WS_B1F + t] = sb1[t % NH] + db1[t];
    wsf[WS_W2F + t] = sw2[t % NH] * dw2[t];
  }
  if (t < ND) wsf[WS_B2F + t] = sb2[0] + db2[t];
  if (t < 8) counts[t] = 0;
}

__global__ void k_count(const int* __restrict__ pid, const float* __restrict__ dl_b,
                        int* __restrict__ counts, float* __restrict__ out) {
  int b = blockIdx.x * 256 + threadIdx.x;
  if (b >= NB) return;
  int p = pid[b];
  if (p > 0) atomicAdd(&counts[p - 1], 1);
  else out[b] = dl_b[0];   // padding: e_pid row is zeros -> logits = dl_b exactly
}

__global__ void k_scan(const int* __restrict__ counts, int* __restrict__ offs,
                       int* __restrict__ curs) {
  if (threadIdx.x == 0) {
    int acc = 0;
    for (int d = 0; d < ND; ++d) { offs[d] = acc; curs[d] = acc; acc += counts[d]; }
  }
}

__global__ void k_fill(const int* __restrict__ pid, int* __restrict__ curs,
                       int* __restrict__ list) {
  int b = blockIdx.x * 256 + threadIdx.x;
  if (b >= NB) return;
  int p = pid[b];
  if (p > 0) { int pos = atomicAdd(&curs[p - 1], 1); list[pos] = b; }
}

// lane = sample; one wave per 64 samples of a single (uniform) domain.
// All weight accesses are wave-uniform -> scalar loads; FMAs are v_fmac s,v.
__global__ void k_main(const int* __restrict__ feats, const float* __restrict__ emb_pid,
                       const float* __restrict__ emb_feats, const float* __restrict__ dl_w,
                       const float* __restrict__ dl_b, const float* __restrict__ wsf,
                       const int* __restrict__ counts, const int* __restrict__ offs,
                       const int* __restrict__ list, float* __restrict__ out) {
  int d = __builtin_amdgcn_readfirstlane(blockIdx.x & 7);
  const int widx = blockIdx.x >> 3;
  const int nw = gridDim.x >> 3;
  const int c = counts[d];
  const int base = offs[d];
  const int lane = threadIdx.x;
  const float* __restrict__ Wd  = wsf + WS_W1F + d * (NIN * NH);
  const float* __restrict__ b1d = wsf + WS_B1F + d * NH;
  const float* __restrict__ w2d = wsf + WS_W2F + d * NH;
  const float b2  = wsf[WS_B2F + d];
  const float dlb = dl_b[0];

  for (int g = widx; g * 64 < c; g += nw) {
    const int k = g * 64 + lane;
    const bool act = k < c;
    const int b = act ? list[base + k] : 0;

    float h[NH];
#pragma unroll
    for (int j = 0; j < NH; ++j) h[j] = b1d[j];

    // field 0: e_pid row — wave-uniform (pid == d+1 for every sample in bucket)
    float dlacc = dlb;
    {
      const float* __restrict__ row = emb_pid + (d + 1) * NE;
#pragma unroll
      for (int i = 0; i < NE; ++i) {
        float xv = fmaxf(row[i], 0.0f);
        dlacc = fmaf(xv, dl_w[i], dlacc);
        const float* __restrict__ wr = Wd + i * NH;
#pragma unroll
        for (int j = 0; j < NH; ++j) h[j] = fmaf(xv, wr[j], h[j]);
      }
    }

    // fields 1..9: per-lane gathers of 64B rows
    int fv = act ? feats[b * NF] : 0;
#pragma unroll 1
    for (int f = 0; f < NF; ++f) {
      const float4* __restrict__ r4 =
          (const float4*)(emb_feats + ((size_t)f * (NV + 1) + (size_t)fv) * NE);
      float4 a0 = r4[0], a1 = r4[1], a2 = r4[2], a3 = r4[3];
      if (f + 1 < NF) fv = act ? feats[b * NF + f + 1] : 0;  // prefetch next index
      float x[NE] = {a0.x, a0.y, a0.z, a0.w, a1.x, a1.y, a1.z, a1.w,
                     a2.x, a2.y, a2.z, a2.w, a3.x, a3.y, a3.z, a3.w};
      const float* __restrict__ wr = Wd + (NE + f * NE) * NH;
#pragma unroll
      for (int i = 0; i < NE; ++i) {
        float xv = fmaxf(x[i], 0.0f);
#pragma unroll
        for (int j = 0; j < NH; ++j) h[j] = fmaf(xv, wr[i * NH + j], h[j]);
      }
    }

    float logit = b2;
#pragma unroll
    for (int j = 0; j < NH; ++j) logit = fmaf(fmaxf(h[j], 0.0f), w2d[j], logit);
    if (act) out[b] = logit + dlacc;
  }
}

extern "C" void kernel_launch(void* const* d_in, const int* in_sizes, int n_in,
                              void* d_out, int out_size, void* d_ws, size_t ws_size,
                              hipStream_t stream) {
  const int*   pid      = (const int*)d_in[0];
  const int*   feats    = (const int*)d_in[1];
  const float* emb_pid  = (const float*)d_in[2];
  const float* emb_f    = (const float*)d_in[3];
  const float* sw1      = (const float*)d_in[4];
  const float* dw1      = (const float*)d_in[5];
  const float* sb1      = (const float*)d_in[6];
  const float* db1      = (const float*)d_in[7];
  const float* sw2      = (const float*)d_in[8];
  const float* dw2      = (const float*)d_in[9];
  const float* sb2      = (const float*)d_in[10];
  const float* db2      = (const float*)d_in[11];
  const float* dl_w     = (const float*)d_in[12];
  const float* dl_b     = (const float*)d_in[13];
  float* out = (float*)d_out;
  float* wsf = (float*)d_ws;
  int*   wsi = (int*)d_ws;
  int* counts = wsi + WS_COUNTS;
  int* curs   = wsi + WS_CURS;
  int* offsp  = wsi + WS_OFFS;
  int* list   = wsi + WS_LIST;

  k_fuse<<<(ND * NIN * NH + 255) / 256, 256, 0, stream>>>(sw1, dw1, sb1, db1, sw2, dw2,
                                                          sb2, db2, wsf, counts);
  k_count<<<NB / 256, 256, 0, stream>>>(pid, dl_b, counts, out);
  k_scan<<<1, 64, 0, stream>>>(counts, offsp, curs);
  k_fill<<<NB / 256, 256, 0, stream>>>(pid, curs, list);
  k_main<<<2048, 64, 0, stream>>>(feats, emb_pid, emb_f, dl_w, dl_b, wsf,
                                  counts, offsp, list, out);
}

// Round 2
// 127.072 us; speedup vs baseline: 4.9173x; 4.9173x over previous
//
#include <hip/hip_runtime.h>

#define NB 65536
#define ND 8
#define NE 16
#define NH 80
#define NF 9
#define NV 100000
#define NIN 160

// ws layout in 4-byte units
#define WS_W1F    0          // 102400 floats: fused W1 per domain (D,IN,H)
#define WS_B1F    102400     // 640
#define WS_W2F    103040     // 640
#define WS_B2F    103680     // 8
#define WS_COUNTS 103712     // 8 counters, stride 32 (128B apart)
#define WS_CURS   103968     // 8 cursors, stride 32
#define WS_OFFS   104224     // 8 ints
#define WS_LIST   104256     // up to 65536 ints

__global__ void k_fuse(const float* __restrict__ sw1, const float* __restrict__ dw1,
                       const float* __restrict__ sb1, const float* __restrict__ db1,
                       const float* __restrict__ sw2, const float* __restrict__ dw2,
                       const float* __restrict__ sb2, const float* __restrict__ db2,
                       float* __restrict__ wsf, int* __restrict__ counts) {
  int t = blockIdx.x * 256 + threadIdx.x;
  if (t < ND * NIN * NH) wsf[WS_W1F + t] = sw1[t % (NIN * NH)] * dw1[t];
  if (t < ND * NH) {
    wsf[WS_B1F + t] = sb1[t % NH] + db1[t];
    wsf[WS_W2F + t] = sw2[t % NH] * dw2[t];
  }
  if (t < ND) wsf[WS_B2F + t] = sb2[0] + db2[t];
  if (t < 256) counts[t] = 0;
}

// ballot-based histogram: <=8 global atomics per block, counters 128B apart
__global__ void k_count(const int* __restrict__ pid, const float* __restrict__ dl_b,
                        int* __restrict__ counts, float* __restrict__ out) {
  int b = blockIdx.x * 256 + threadIdx.x;
  int p = pid[b];
  if (p == 0) out[b] = dl_b[0];  // padding: e_pid row is zeros -> logits = dl_b exactly
  __shared__ int blk[ND];
  if (threadIdx.x < ND) blk[threadIdx.x] = 0;
  __syncthreads();
#pragma unroll
  for (int d = 0; d < ND; ++d) {
    unsigned long long m = __ballot(p == d + 1);
    if ((threadIdx.x & 63) == 0 && m) atomicAdd(&blk[d], (int)__popcll(m));
  }
  __syncthreads();
  if (threadIdx.x < ND && blk[threadIdx.x])
    atomicAdd(&counts[threadIdx.x * 32], blk[threadIdx.x]);
}

__global__ void k_scan(const int* __restrict__ counts, int* __restrict__ offs,
                       int* __restrict__ curs) {
  if (threadIdx.x == 0) {
    int acc = 0;
    for (int d = 0; d < ND; ++d) { offs[d] = acc; curs[d * 32] = acc; acc += counts[d * 32]; }
  }
}

// ballot-ranked scatter: per block, one atomicAdd per domain reserves a range
__global__ void k_fill(const int* __restrict__ pid, int* __restrict__ curs,
                       int* __restrict__ list) {
  int b = blockIdx.x * 256 + threadIdx.x;
  int p = pid[b];
  int wave = threadIdx.x >> 6, lane = threadIdx.x & 63;
  __shared__ int wcnt[4][ND];
  __shared__ int wbase[4][ND];
  int rank = 0;
#pragma unroll
  for (int d = 0; d < ND; ++d) {
    unsigned long long m = __ballot(p == d + 1);
    if (lane == 0) wcnt[wave][d] = (int)__popcll(m);
    if (p == d + 1) rank = (int)__popcll(m & ((1ull << lane) - 1ull));
  }
  __syncthreads();
  if (threadIdx.x < ND) {
    int d = threadIdx.x;
    int tot = wcnt[0][d] + wcnt[1][d] + wcnt[2][d] + wcnt[3][d];
    int bse = tot ? atomicAdd(&curs[d * 32], tot) : 0;
    for (int w = 0; w < 4; ++w) { wbase[w][d] = bse; bse += wcnt[w][d]; }
  }
  __syncthreads();
  if (p > 0) list[wbase[wave][p - 1] + rank] = b;
}

// block = 256 threads = 4 waves; lane = sample, wave w owns h[j] for j in [w*20, w*20+20)
// bucket-uniform work (e_pid field, domain_logits) hoisted out of the sample loop
__global__ __launch_bounds__(256) void k_main(
    const int* __restrict__ feats, const float* __restrict__ emb_pid,
    const float* __restrict__ emb_feats, const float* __restrict__ dl_w,
    const float* __restrict__ dl_b, const float* __restrict__ wsf,
    const int* __restrict__ counts, const int* __restrict__ offs,
    const int* __restrict__ list, float* __restrict__ out) {
  const int d = blockIdx.x & 7;
  const int widx = blockIdx.x >> 3;
  const int nw = gridDim.x >> 3;
  const int wave = threadIdx.x >> 6;
  const int lane = threadIdx.x & 63;
  const int c = counts[d * 32];
  const int base = offs[d];
  const int j0 = wave * 20;
  const float* __restrict__ Wd  = wsf + WS_W1F + d * (NIN * NH);
  const float* __restrict__ b1d = wsf + WS_B1F + d * NH;
  const float* __restrict__ w2d = wsf + WS_W2F + d * NH;
  const float b2 = wsf[WS_B2F + d];

  // bucket-uniform: domain logit and e_pid-field contribution to h
  float dlacc = dl_b[0];
  float hb[20];
#pragma unroll
  for (int j = 0; j < 20; ++j) hb[j] = b1d[j0 + j];
  {
    const float* __restrict__ row = emb_pid + (d + 1) * NE;
#pragma unroll
    for (int i = 0; i < NE; ++i) {
      float xv = fmaxf(row[i], 0.0f);
      dlacc = fmaf(xv, dl_w[i], dlacc);
#pragma unroll
      for (int j = 0; j < 20; ++j) hb[j] = fmaf(xv, Wd[i * NH + j0 + j], hb[j]);
    }
  }

  __shared__ float red[4][64];

  for (int g = widx; g * 64 < c; g += nw) {
    const int k = g * 64 + lane;
    const bool act = k < c;
    const int b = act ? list[base + k] : 0;

    float h[20];
#pragma unroll
    for (int j = 0; j < 20; ++j) h[j] = hb[j];

    int fv = act ? feats[b * NF] : 0;
#pragma unroll 1
    for (int f = 0; f < NF; ++f) {
      const float4* __restrict__ r4 =
          (const float4*)(emb_feats + ((size_t)f * (NV + 1) + (size_t)fv) * NE);
      float4 a0 = r4[0], a1 = r4[1], a2 = r4[2], a3 = r4[3];
      if (f + 1 < NF) fv = act ? feats[b * NF + f + 1] : 0;  // prefetch next index
      float x[NE] = {a0.x, a0.y, a0.z, a0.w, a1.x, a1.y, a1.z, a1.w,
                     a2.x, a2.y, a2.z, a2.w, a3.x, a3.y, a3.z, a3.w};
      const float* __restrict__ wr = Wd + (NE + f * NE) * NH + j0;
#pragma unroll
      for (int i = 0; i < NE; ++i) {
        float xv = fmaxf(x[i], 0.0f);
#pragma unroll
        for (int j = 0; j < 20; ++j) h[j] = fmaf(xv, wr[i * NH + j], h[j]);
      }
    }

    float part = 0.0f;
#pragma unroll
    for (int j = 0; j < 20; ++j) part = fmaf(fmaxf(h[j], 0.0f), w2d[j0 + j], part);
    red[wave][lane] = part;
    __syncthreads();
    if (wave == 0 && act)
      out[b] = red[0][lane] + red[1][lane] + red[2][lane] + red[3][lane] + b2 + dlacc;
    __syncthreads();
  }
}

extern "C" void kernel_launch(void* const* d_in, const int* in_sizes, int n_in,
                              void* d_out, int out_size, void* d_ws, size_t ws_size,
                              hipStream_t stream) {
  const int*   pid      = (const int*)d_in[0];
  const int*   feats    = (const int*)d_in[1];
  const float* emb_pid  = (const float*)d_in[2];
  const float* emb_f    = (const float*)d_in[3];
  const float* sw1      = (const float*)d_in[4];
  const float* dw1      = (const float*)d_in[5];
  const float* sb1      = (const float*)d_in[6];
  const float* db1      = (const float*)d_in[7];
  const float* sw2      = (const float*)d_in[8];
  const float* dw2      = (const float*)d_in[9];
  const float* sb2      = (const float*)d_in[10];
  const float* db2      = (const float*)d_in[11];
  const float* dl_w     = (const float*)d_in[12];
  const float* dl_b     = (const float*)d_in[13];
  float* out = (float*)d_out;
  float* wsf = (float*)d_ws;
  int*   wsi = (int*)d_ws;
  int* counts = wsi + WS_COUNTS;
  int* curs   = wsi + WS_CURS;
  int* offsp  = wsi + WS_OFFS;
  int* list   = wsi + WS_LIST;

  k_fuse<<<(ND * NIN * NH + 255) / 256, 256, 0, stream>>>(sw1, dw1, sb1, db1, sw2, dw2,
                                                          sb2, db2, wsf, counts);
  k_count<<<NB / 256, 256, 0, stream>>>(pid, dl_b, counts, out);
  k_scan<<<1, 64, 0, stream>>>(counts, offsp, curs);
  k_fill<<<NB / 256, 256, 0, stream>>>(pid, curs, list);
  k_main<<<1024, 256, 0, stream>>>(feats, emb_pid, emb_f, dl_w, dl_b, wsf,
                                   counts, offsp, list, out);
}

// Round 3
// 42.721 us; speedup vs baseline: 14.6264x; 2.9745x over previous
//
#include <hip/hip_runtime.h>

#define NB 65536
#define ND 8
#define NE 16
#define NH 80
#define NF 9
#define NV 100000
#define NIN 160

typedef __attribute__((ext_vector_type(8))) short short8;    // 8 bf16 (4 VGPRs)
typedef __attribute__((ext_vector_type(4))) float float4v;   // MFMA acc

// ws layout in 4-byte units
#define WS_W1BF   0        // bf16 fused W1, [d][n][k] transposed: 8*80*160 ushort = 51200 u32
#define WS_B1F    51200    // 640 f32 [d][h]
#define WS_W2F    51840    // 640 f32 [d][h]
#define WS_B2F    52480    // 8 f32
#define WS_COUNTS 52512    // 8 counters, stride 32 (128B apart)
#define WS_CURS   52768    // 8 cursors, stride 32
#define WS_OFFS   53024    // 8 ints
#define WS_LIST   53056    // up to 65536 ints

__device__ inline unsigned short f2bf(float x) {   // RNE f32->bf16
  unsigned int u = __float_as_uint(x);
  return (unsigned short)((u + 0x7fffu + ((u >> 16) & 1u)) >> 16);
}

__global__ void k_fuse(const float* __restrict__ sw1, const float* __restrict__ dw1,
                       const float* __restrict__ sb1, const float* __restrict__ db1,
                       const float* __restrict__ sw2, const float* __restrict__ dw2,
                       const float* __restrict__ sb2, const float* __restrict__ db2,
                       unsigned int* __restrict__ w1bf, float* __restrict__ wsf,
                       int* __restrict__ counts) {
  int t = blockIdx.x * 256 + threadIdx.x;
  if (t < ND * NH * (NIN / 2)) {          // one uint = 2 consecutive k of W1bf[d][n][k]
    int d = t / (NH * (NIN / 2));
    int r = t % (NH * (NIN / 2));
    int n = r / (NIN / 2);
    int kp = r % (NIN / 2);
    int k0 = kp * 2;
    float a = sw1[k0 * NH + n] * dw1[d * NIN * NH + k0 * NH + n];
    float b = sw1[(k0 + 1) * NH + n] * dw1[d * NIN * NH + (k0 + 1) * NH + n];
    w1bf[t] = (unsigned int)f2bf(a) | ((unsigned int)f2bf(b) << 16);
  }
  if (t < ND * NH) {
    wsf[WS_B1F + t] = sb1[t % NH] + db1[t];
    wsf[WS_W2F + t] = sw2[t % NH] * dw2[t];
  }
  if (t < ND) wsf[WS_B2F + t] = sb2[0] + db2[t];
  if (t < 512) ((int*)wsf)[WS_COUNTS + t] = 0;   // zero counters + cursors
}

// ballot histogram: <=8 global atomics per block, counters 128B apart
__global__ void k_count(const int* __restrict__ pid, const float* __restrict__ dl_b,
                        int* __restrict__ counts, float* __restrict__ out) {
  int b = blockIdx.x * 256 + threadIdx.x;
  int p = pid[b];
  if (p == 0) out[b] = dl_b[0];  // padding: e_pid row is zeros -> logits = dl_b exactly
  __shared__ int blk[ND];
  if (threadIdx.x < ND) blk[threadIdx.x] = 0;
  __syncthreads();
#pragma unroll
  for (int d = 0; d < ND; ++d) {
    unsigned long long m = __ballot(p == d + 1);
    if ((threadIdx.x & 63) == 0 && m) atomicAdd(&blk[d], (int)__popcll(m));
  }
  __syncthreads();
  if (threadIdx.x < ND && blk[threadIdx.x])
    atomicAdd(&counts[threadIdx.x * 32], blk[threadIdx.x]);
}

__global__ void k_scan(const int* __restrict__ counts, int* __restrict__ offs,
                       int* __restrict__ curs) {
  if (threadIdx.x == 0) {
    int acc = 0;
    for (int d = 0; d < ND; ++d) { offs[d] = acc; curs[d * 32] = acc; acc += counts[d * 32]; }
  }
}

// ballot-ranked scatter: one atomicAdd per (block, domain)
__global__ void k_fill(const int* __restrict__ pid, int* __restrict__ curs,
                       int* __restrict__ list) {
  int b = blockIdx.x * 256 + threadIdx.x;
  int p = pid[b];
  int wave = threadIdx.x >> 6, lane = threadIdx.x & 63;
  __shared__ int wcnt[4][ND];
  __shared__ int wbase[4][ND];
  int rank = 0;
#pragma unroll
  for (int d = 0; d < ND; ++d) {
    unsigned long long m = __ballot(p == d + 1);
    if (lane == 0) wcnt[wave][d] = (int)__popcll(m);
    if (p == d + 1) rank = (int)__popcll(m & ((1ull << lane) - 1ull));
  }
  __syncthreads();
  if (threadIdx.x < ND) {
    int d = threadIdx.x;
    int tot = wcnt[0][d] + wcnt[1][d] + wcnt[2][d] + wcnt[3][d];
    int bse = tot ? atomicAdd(&curs[d * 32], tot) : 0;
    for (int w = 0; w < 4; ++w) { wbase[w][d] = bse; bse += wcnt[w][d]; }
  }
  __syncthreads();
  if (p > 0) list[wbase[wave][p - 1] + rank] = b;
}

// MFMA main: block = 4 waves; 64 samples/iter; wave w owns M-tile w, 5 N-tiles.
// A = relu'd bf16 embeddings in sA[64][168] (padded); B = fused bf16 W1 [n][k] in sB.
// Layer 2 fused in epilogue (relu + dot w2 + cross-lane reduce).
__global__ __launch_bounds__(256) void k_main(
    const int* __restrict__ feats, const float* __restrict__ emb_pid,
    const float* __restrict__ emb_feats, const float* __restrict__ dl_w,
    const float* __restrict__ dl_b, const unsigned int* __restrict__ w1bf,
    const float* __restrict__ wsf, const int* __restrict__ counts,
    const int* __restrict__ offs, const int* __restrict__ list,
    float* __restrict__ out) {
  const int d = blockIdx.x & 7;
  const int widx = blockIdx.x >> 3;
  const int nw = gridDim.x >> 3;
  const int c = counts[d * 32];
  const int base = offs[d];
  const int t = threadIdx.x;
  const int wave = t >> 6, lane = t & 63;

  __shared__ unsigned short sA[64][168];   // 21504 B
  __shared__ unsigned short sB[80][168];   // 26880 B

  // stage fused W1 (bf16, [n][k]) into LDS once per block
  const unsigned int* __restrict__ wb = w1bf + d * (NH * (NIN / 2));
  for (int i = t; i < NH * (NIN / 2); i += 256) {
    int n = i / (NIN / 2), kp = i % (NIN / 2);
    ((unsigned int*)&sB[n][0])[kp] = wb[i];
  }

  // bucket-uniform: domain logit + relu'd e_pid row (bf16-packed)
  float dlacc = dl_b[0];
  unsigned int ep[8];
  {
    const float* __restrict__ row = emb_pid + (d + 1) * NE;
#pragma unroll
    for (int i = 0; i < NE; i += 2) {
      float x0 = fmaxf(row[i], 0.f), x1 = fmaxf(row[i + 1], 0.f);
      dlacc = fmaf(x0, dl_w[i], dlacc);
      dlacc = fmaf(x1, dl_w[i + 1], dlacc);
      ep[i >> 1] = (unsigned int)f2bf(x0) | ((unsigned int)f2bf(x1) << 16);
    }
  }
  const float b2 = wsf[WS_B2F + d];
  float b1l[5], w2l[5];
#pragma unroll
  for (int nt = 0; nt < 5; ++nt) {
    b1l[nt] = wsf[WS_B1F + d * NH + nt * 16 + (lane & 15)];
    w2l[nt] = wsf[WS_W2F + d * NH + nt * 16 + (lane & 15)];
  }

  for (int g = widx; g * 64 < c; g += nw) {
    // ---- stage A: 4 threads per sample, each converts one float4 per field ----
    const int s = t >> 2;
    const int q = t & 3;
    const int kidx = g * 64 + s;
    const int b = (kidx < c) ? list[base + kidx] : list[base];
    if (q < 2) {  // e_pid columns 0..15 (uniform row)
      unsigned int* dst = (unsigned int*)&sA[s][0];
#pragma unroll
      for (int j = 0; j < 4; ++j) dst[q * 4 + j] = ep[q * 4 + j];
    }
    int fv = feats[b * NF];
#pragma unroll 1
    for (int f = 0; f < NF; ++f) {
      const float4* __restrict__ src =
          (const float4*)(emb_feats + ((size_t)f * (NV + 1) + (size_t)fv) * NE);
      float4 v = src[q];
      if (f + 1 < NF) fv = feats[b * NF + f + 1];  // prefetch next index
      unsigned int p0 = (unsigned int)f2bf(fmaxf(v.x, 0.f)) |
                        ((unsigned int)f2bf(fmaxf(v.y, 0.f)) << 16);
      unsigned int p1 = (unsigned int)f2bf(fmaxf(v.z, 0.f)) |
                        ((unsigned int)f2bf(fmaxf(v.w, 0.f)) << 16);
      unsigned int* dst = (unsigned int*)&sA[s][16 + f * 16];
      dst[q * 2] = p0;
      dst[q * 2 + 1] = p1;
    }
    __syncthreads();

    // ---- MFMA: A lane l -> row l&15, k = (l>>4)*8+e ; B lane l -> col l&15 ----
    float4v acc[5];
#pragma unroll
    for (int nt = 0; nt < 5; ++nt)
      acc[nt] = (float4v){b1l[nt], b1l[nt], b1l[nt], b1l[nt]};
    const int arow = wave * 16 + (lane & 15);
    const int koff = (lane >> 4) * 8;
#pragma unroll
    for (int ks = 0; ks < 5; ++ks) {
      short8 af = *(const short8*)&sA[arow][ks * 32 + koff];
#pragma unroll
      for (int nt = 0; nt < 5; ++nt) {
        short8 bf = *(const short8*)&sB[nt * 16 + (lane & 15)][ks * 32 + koff];
        acc[nt] = __builtin_amdgcn_mfma_f32_16x16x32_bf16(af, bf, acc[nt], 0, 0, 0);
      }
    }

    // ---- layer 2: relu(h) . w2, reduce across the 16-lane n-groups ----
    float p[4];
#pragma unroll
    for (int r = 0; r < 4; ++r) {
      float a2 = 0.f;
#pragma unroll
      for (int nt = 0; nt < 5; ++nt) a2 = fmaf(fmaxf(acc[nt][r], 0.f), w2l[nt], a2);
      p[r] = a2;
    }
#pragma unroll
    for (int r = 0; r < 4; ++r) {
      p[r] += __shfl_xor(p[r], 1);
      p[r] += __shfl_xor(p[r], 2);
      p[r] += __shfl_xor(p[r], 4);
      p[r] += __shfl_xor(p[r], 8);
    }
    if ((lane & 15) == 0) {
      int srow = wave * 16 + (lane >> 4) * 4;
#pragma unroll
      for (int r = 0; r < 4; ++r) {
        int kk = g * 64 + srow + r;
        if (kk < c) out[list[base + kk]] = p[r] + b2 + dlacc;
      }
    }
    __syncthreads();
  }
}

extern "C" void kernel_launch(void* const* d_in, const int* in_sizes, int n_in,
                              void* d_out, int out_size, void* d_ws, size_t ws_size,
                              hipStream_t stream) {
  const int*   pid      = (const int*)d_in[0];
  const int*   feats    = (const int*)d_in[1];
  const float* emb_pid  = (const float*)d_in[2];
  const float* emb_f    = (const float*)d_in[3];
  const float* sw1      = (const float*)d_in[4];
  const float* dw1      = (const float*)d_in[5];
  const float* sb1      = (const float*)d_in[6];
  const float* db1      = (const float*)d_in[7];
  const float* sw2      = (const float*)d_in[8];
  const float* dw2      = (const float*)d_in[9];
  const float* sb2      = (const float*)d_in[10];
  const float* db2      = (const float*)d_in[11];
  const float* dl_w     = (const float*)d_in[12];
  const float* dl_b     = (const float*)d_in[13];
  float* out = (float*)d_out;
  float* wsf = (float*)d_ws;
  int*   wsi = (int*)d_ws;
  unsigned int* w1bf = (unsigned int*)d_ws;  // at offset WS_W1BF = 0
  int* counts = wsi + WS_COUNTS;
  int* curs   = wsi + WS_CURS;
  int* offsp  = wsi + WS_OFFS;
  int* list   = wsi + WS_LIST;

  k_fuse<<<(ND * NH * (NIN / 2) + 255) / 256, 256, 0, stream>>>(
      sw1, dw1, sb1, db1, sw2, dw2, sb2, db2, w1bf, wsf, counts);
  k_count<<<NB / 256, 256, 0, stream>>>(pid, dl_b, counts, out);
  k_scan<<<1, 64, 0, stream>>>(counts, offsp, curs);
  k_fill<<<NB / 256, 256, 0, stream>>>(pid, curs, list);
  k_main<<<1024, 256, 0, stream>>>(feats, emb_pid, emb_f, dl_w, dl_b, w1bf, wsf,
                                   counts, offsp, list, out);
}

// Round 4
// 33.620 us; speedup vs baseline: 18.5859x; 1.2707x over previous
//
#include <hip/hip_runtime.h>

#define NB 65536
#define ND 8
#define NE 16
#define NH 80
#define NF 9
#define NV 100000
#define NIN 160

typedef __attribute__((ext_vector_type(8))) short short8;    // 8 bf16 (4 VGPRs)
typedef __attribute__((ext_vector_type(4))) float float4v;   // MFMA acc

// ws layout in 4-byte units
#define WS_W1BF   0        // bf16 fused W1, [d][n][k] transposed: 8*80*160 ushort = 51200 u32
#define WS_B1F    51200    // 640 f32 [d][h]
#define WS_W2F    51840    // 640 f32 [d][h]
#define WS_B2F    52480    // 8 f32
#define WS_CURS   52512    // 8 cursors, stride 32 (128B apart)
#define WS_LIST   52768    // 8 regions of NB ints: domain d at WS_LIST + d*NB

__device__ inline unsigned short f2bf(float x) {   // RNE f32->bf16
  unsigned int u = __float_as_uint(x);
  return (unsigned short)((u + 0x7fffu + ((u >> 16) & 1u)) >> 16);
}

__global__ void k_fuse(const float* __restrict__ sw1, const float* __restrict__ dw1,
                       const float* __restrict__ sb1, const float* __restrict__ db1,
                       const float* __restrict__ sw2, const float* __restrict__ dw2,
                       const float* __restrict__ sb2, const float* __restrict__ db2,
                       unsigned int* __restrict__ w1bf, float* __restrict__ wsf) {
  int t = blockIdx.x * 256 + threadIdx.x;
  if (t < ND * NH * (NIN / 2)) {          // one uint = 2 consecutive k of W1bf[d][n][k]
    int d = t / (NH * (NIN / 2));
    int r = t % (NH * (NIN / 2));
    int n = r / (NIN / 2);
    int kp = r % (NIN / 2);
    int k0 = kp * 2;
    float a = sw1[k0 * NH + n] * dw1[d * NIN * NH + k0 * NH + n];
    float b = sw1[(k0 + 1) * NH + n] * dw1[d * NIN * NH + (k0 + 1) * NH + n];
    w1bf[t] = (unsigned int)f2bf(a) | ((unsigned int)f2bf(b) << 16);
  }
  if (t < ND * NH) {
    wsf[WS_B1F + t] = sb1[t % NH] + db1[t];
    wsf[WS_W2F + t] = sw2[t % NH] * dw2[t];
  }
  if (t < ND) wsf[WS_B2F + t] = sb2[0] + db2[t];
  if (t >= 256 && t < 512) ((int*)wsf)[WS_CURS + (t - 256)] = 0;  // zero cursors
}

// count + placement fused: ballot-ranked scatter, one atomicAdd per (block, domain).
// Each domain owns a private NB-sized list region, so no prefix scan is needed;
// the cursor doubles as the final count for k_main. Placement order is atomic-
// nondeterministic but each sample's output is computed independently -> d_out
// is deterministic.
__global__ void k_fill(const int* __restrict__ pid, const float* __restrict__ dl_b,
                       int* __restrict__ curs, int* __restrict__ list,
                       float* __restrict__ out) {
  int b = blockIdx.x * 256 + threadIdx.x;
  int p = pid[b];
  if (p == 0) out[b] = dl_b[0];  // padding: e_pid row is zeros -> logits = dl_b exactly
  int wave = threadIdx.x >> 6, lane = threadIdx.x & 63;
  __shared__ int wcnt[4][ND];
  __shared__ int wbase[4][ND];
  int rank = 0;
#pragma unroll
  for (int d = 0; d < ND; ++d) {
    unsigned long long m = __ballot(p == d + 1);
    if (lane == 0) wcnt[wave][d] = (int)__popcll(m);
    if (p == d + 1) rank = (int)__popcll(m & ((1ull << lane) - 1ull));
  }
  __syncthreads();
  if (threadIdx.x < ND) {
    int d = threadIdx.x;
    int tot = wcnt[0][d] + wcnt[1][d] + wcnt[2][d] + wcnt[3][d];
    int bse = tot ? atomicAdd(&curs[d * 32], tot) : 0;
    for (int w = 0; w < 4; ++w) { wbase[w][d] = bse; bse += wcnt[w][d]; }
  }
  __syncthreads();
  if (p > 0) list[(p - 1) * NB + wbase[wave][p - 1] + rank] = b;
}

// MFMA main: block = 4 waves; 64 samples/iter; wave w owns M-tile w, 5 N-tiles.
// A = relu'd bf16 embeddings in sA[64][168] (padded); B = fused bf16 W1 [n][k] in sB.
// All 9 feat indices hoisted up front -> 9 independent float4 gathers (depth 2,
// not a 9-deep dependent chain). Layer 2 fused in epilogue.
__global__ __launch_bounds__(256) void k_main(
    const int* __restrict__ feats, const float* __restrict__ emb_pid,
    const float* __restrict__ emb_feats, const float* __restrict__ dl_w,
    const float* __restrict__ dl_b, const unsigned int* __restrict__ w1bf,
    const float* __restrict__ wsf, const int* __restrict__ curs,
    const int* __restrict__ list, float* __restrict__ out) {
  const int d = blockIdx.x & 7;
  const int widx = blockIdx.x >> 3;
  const int nw = gridDim.x >> 3;
  const int c = curs[d * 32];
  const int* __restrict__ dlist = list + d * NB;
  const int t = threadIdx.x;
  const int wave = t >> 6, lane = t & 63;

  __shared__ unsigned short sA[64][168];   // 21504 B
  __shared__ unsigned short sB[80][168];   // 26880 B

  // stage fused W1 (bf16, [n][k]) into LDS once per block
  const unsigned int* __restrict__ wb = w1bf + d * (NH * (NIN / 2));
  for (int i = t; i < NH * (NIN / 2); i += 256) {
    int n = i / (NIN / 2), kp = i % (NIN / 2);
    ((unsigned int*)&sB[n][0])[kp] = wb[i];
  }

  // bucket-uniform: domain logit + relu'd e_pid row (bf16-packed)
  float dlacc = dl_b[0];
  unsigned int ep[8];
  {
    const float* __restrict__ row = emb_pid + (d + 1) * NE;
#pragma unroll
    for (int i = 0; i < NE; i += 2) {
      float x0 = fmaxf(row[i], 0.f), x1 = fmaxf(row[i + 1], 0.f);
      dlacc = fmaf(x0, dl_w[i], dlacc);
      dlacc = fmaf(x1, dl_w[i + 1], dlacc);
      ep[i >> 1] = (unsigned int)f2bf(x0) | ((unsigned int)f2bf(x1) << 16);
    }
  }
  const float b2 = wsf[WS_B2F + d];
  float b1l[5], w2l[5];
#pragma unroll
  for (int nt = 0; nt < 5; ++nt) {
    b1l[nt] = wsf[WS_B1F + d * NH + nt * 16 + (lane & 15)];
    w2l[nt] = wsf[WS_W2F + d * NH + nt * 16 + (lane & 15)];
  }

  for (int g = widx; g * 64 < c; g += nw) {
    // ---- stage A: 4 threads per sample, each converts one float4 per field ----
    const int s = t >> 2;
    const int q = t & 3;
    const int kidx = g * 64 + s;
    const int b = (kidx < c) ? dlist[kidx] : dlist[0];
    if (q < 2) {  // e_pid columns 0..15 (uniform row)
      unsigned int* dst = (unsigned int*)&sA[s][0];
#pragma unroll
      for (int j = 0; j < 4; ++j) dst[q * 4 + j] = ep[q * 4 + j];
    }
    int idx[NF];
#pragma unroll
    for (int f = 0; f < NF; ++f) idx[f] = feats[b * NF + f];
    float4 v[NF];
#pragma unroll
    for (int f = 0; f < NF; ++f)
      v[f] = ((const float4*)(emb_feats + ((size_t)f * (NV + 1) + (size_t)idx[f]) * NE))[q];
#pragma unroll
    for (int f = 0; f < NF; ++f) {
      unsigned int p0 = (unsigned int)f2bf(fmaxf(v[f].x, 0.f)) |
                        ((unsigned int)f2bf(fmaxf(v[f].y, 0.f)) << 16);
      unsigned int p1 = (unsigned int)f2bf(fmaxf(v[f].z, 0.f)) |
                        ((unsigned int)f2bf(fmaxf(v[f].w, 0.f)) << 16);
      unsigned int* dst = (unsigned int*)&sA[s][16 + f * 16];
      dst[q * 2] = p0;
      dst[q * 2 + 1] = p1;
    }
    __syncthreads();

    // ---- MFMA: A lane l -> row l&15, k = (l>>4)*8+e ; B lane l -> col l&15 ----
    float4v acc[5];
#pragma unroll
    for (int nt = 0; nt < 5; ++nt)
      acc[nt] = (float4v){b1l[nt], b1l[nt], b1l[nt], b1l[nt]};
    const int arow = wave * 16 + (lane & 15);
    const int koff = (lane >> 4) * 8;
#pragma unroll
    for (int ks = 0; ks < 5; ++ks) {
      short8 af = *(const short8*)&sA[arow][ks * 32 + koff];
#pragma unroll
      for (int nt = 0; nt < 5; ++nt) {
        short8 bf = *(const short8*)&sB[nt * 16 + (lane & 15)][ks * 32 + koff];
        acc[nt] = __builtin_amdgcn_mfma_f32_16x16x32_bf16(af, bf, acc[nt], 0, 0, 0);
      }
    }

    // ---- layer 2: relu(h) . w2, reduce across the 16-lane n-groups ----
    float p[4];
#pragma unroll
    for (int r = 0; r < 4; ++r) {
      float a2 = 0.f;
#pragma unroll
      for (int nt = 0; nt < 5; ++nt) a2 = fmaf(fmaxf(acc[nt][r], 0.f), w2l[nt], a2);
      p[r] = a2;
    }
#pragma unroll
    for (int r = 0; r < 4; ++r) {
      p[r] += __shfl_xor(p[r], 1);
      p[r] += __shfl_xor(p[r], 2);
      p[r] += __shfl_xor(p[r], 4);
      p[r] += __shfl_xor(p[r], 8);
    }
    if ((lane & 15) == 0) {
      int srow = wave * 16 + (lane >> 4) * 4;
#pragma unroll
      for (int r = 0; r < 4; ++r) {
        int kk = g * 64 + srow + r;
        if (kk < c) out[dlist[kk]] = p[r] + b2 + dlacc;
      }
    }
    __syncthreads();
  }
}

extern "C" void kernel_launch(void* const* d_in, const int* in_sizes, int n_in,
                              void* d_out, int out_size, void* d_ws, size_t ws_size,
                              hipStream_t stream) {
  const int*   pid      = (const int*)d_in[0];
  const int*   feats    = (const int*)d_in[1];
  const float* emb_pid  = (const float*)d_in[2];
  const float* emb_f    = (const float*)d_in[3];
  const float* sw1      = (const float*)d_in[4];
  const float* dw1      = (const float*)d_in[5];
  const float* sb1      = (const float*)d_in[6];
  const float* db1      = (const float*)d_in[7];
  const float* sw2      = (const float*)d_in[8];
  const float* dw2      = (const float*)d_in[9];
  const float* sb2      = (const float*)d_in[10];
  const float* db2      = (const float*)d_in[11];
  const float* dl_w     = (const float*)d_in[12];
  const float* dl_b     = (const float*)d_in[13];
  float* out = (float*)d_out;
  float* wsf = (float*)d_ws;
  int*   wsi = (int*)d_ws;
  unsigned int* w1bf = (unsigned int*)d_ws;  // at offset WS_W1BF = 0
  int* curs = wsi + WS_CURS;
  int* list = wsi + WS_LIST;

  k_fuse<<<(ND * NH * (NIN / 2) + 255) / 256, 256, 0, stream>>>(
      sw1, dw1, sb1, db1, sw2, dw2, sb2, db2, w1bf, wsf);
  k_fill<<<NB / 256, 256, 0, stream>>>(pid, dl_b, curs, list, out);
  k_main<<<1024, 256, 0, stream>>>(feats, emb_pid, emb_f, dl_w, dl_b, w1bf, wsf,
                                   curs, list, out);
}